// Round 4
// baseline (128.124 us; speedup 1.0000x reference)
//
#include <hip/hip_runtime.h>
#include <hip/hip_fp16.h>
#include <math.h>

// ---------------------------------------------------------------------------
// FocalLoss: geodetic->ECEF->ENU error -> distance -> focal-weighted RMS.
// 3-kernel pipeline: pass1 (dist -> fp16 ws, per-block max) ->
// pass2 (fold blockmax inline + focal + per-block partial) -> final.
//
// R16 = R15 with pass1 occupancy restructure.
// R15 post-mortem: pass1 (~30us) is latency-exposure bound, not VALU bound
// (dp-FMA floor ~4us, memory floor 8-16us; harness's 2x256MiB poison fills
// evict inputs from L3 each iteration -> partly HBM-cold reads). The
// 2-group unroll's 24 hoisted float4s (96 VGPR live) forced ~168 VGPR =
// 3 waves/SIMD. R16: 1 group/thread, 3907 blocks, __launch_bounds__(256,4)
// -> 16 waves/CU; sincos8 keeps ILP=8 inside the thread.
//   - fp32 range reduction (rintf quadrant; reduction identity exact for
//     any integer k, cancellation FMAs stay fp64).
//   - pass2: hoist 1/denom out of the loop (kills full-precision div/elem).
// Kept from R14/R15 (error budget <= fp16 dist quantization ~2e-3 m):
//   - sincos8: 4 leading Horner stages in fp32, final stage + combine fp64.
//   - rsqrt: fp32 seed + 1 dp Newton (1.5e-14 rel).
//   - pass2 grid capped at 2048 blocks. No nt loads (R14 lesson).
// ---------------------------------------------------------------------------

#define THREADS 256
#define PART_CAP 8192
#define NB2_CAP 2048
#define BMAX_OFF 64
#define PART_OFF (64 + PART_CAP * 4)                 // doubles, 8-aligned
#define DIST_OFF (1 << 20)                           // 1 MB, 16B-aligned

// ---- 8-wide breadth-first sincos, |x| <= ~3.15 (no Payne-Hanek) ----------
// fdlibm minimax; 4 leading Horner stages in fp32 (contribution < 1e-4,
// fp32 rounding there adds < 2e-10 abs), final stage + combine in fp64.
// Quadrant via fp32 rintf: identity sin(x)=f(r,q) exact for any integer k;
// near-boundary off-by-one only grows |r| to pi/4+1ulp (poly still valid).
// Total abs err ~1e-10 -> ~1e-3 m at N=6.4e6.
__device__ __forceinline__ void sincos8(const double* __restrict__ x,
                                        double* __restrict__ s,
                                        double* __restrict__ c) {
    const float  TWO_OVER_PI_F = 0.636619772367581343076f;
    const double PIO2_HI = 1.57079632679489655800e+00;
    const double PIO2_LO = 6.12323399573676603587e-17;

    double kd[8], r[8], r2[8];
    int q[8];
#pragma unroll
    for (int j = 0; j < 8; ++j) {
        float kf = rintf((float)x[j] * TWO_OVER_PI_F);
        kd[j] = (double)kf;
        q[j] = ((int)kf) & 3;
    }
#pragma unroll
    for (int j = 0; j < 8; ++j) {
        double rr = fma(-kd[j], PIO2_HI, x[j]);
        r[j] = fma(-kd[j], PIO2_LO, rr);
        r2[j] = r[j] * r[j];
    }
    // fp32 high-order tails
    float rf[8], psf[8], pcf[8];
#pragma unroll
    for (int j = 0; j < 8; ++j) rf[j] = (float)r2[j];
#pragma unroll
    for (int j = 0; j < 8; ++j) { psf[j] = -2.50507602534068634195e-08f;
                                  pcf[j] =  2.08757232129817482790e-09f; }
#pragma unroll
    for (int j = 0; j < 8; ++j) { psf[j] = fmaf(psf[j], rf[j],  2.75573137070700676789e-06f);
                                  pcf[j] = fmaf(pcf[j], rf[j], -2.75573143513906633035e-07f); }
#pragma unroll
    for (int j = 0; j < 8; ++j) { psf[j] = fmaf(psf[j], rf[j], -1.98412698298579493134e-04f);
                                  pcf[j] = fmaf(pcf[j], rf[j],  2.48015872894767294178e-05f); }
#pragma unroll
    for (int j = 0; j < 8; ++j) { psf[j] = fmaf(psf[j], rf[j],  8.33333333332248946124e-03f);
                                  pcf[j] = fmaf(pcf[j], rf[j], -1.38888888888741095749e-03f); }
#pragma unroll
    for (int j = 0; j < 8; ++j) {
        double ps = fma((double)psf[j], r2[j], -1.66666666666666324348e-01);
        double pc = fma((double)pcf[j], r2[j],  4.16666666666666019037e-02);
        double sv = fma(r2[j] * r[j], ps, r[j]);
        double cv = fma(r2[j] * r2[j], pc, fma(-0.5, r2[j], 1.0));
        double sr = (q[j] & 1) ? cv : sv;
        double cr = (q[j] & 1) ? sv : cv;
        s[j] = (q[j] & 2) ? -sr : sr;
        c[j] = ((q[j] + 1) & 2) ? -cr : cr;
    }
}

// ---- 4 elements, breadth-first sincos, NO rotation (|R d| == |d|) ----
__device__ __forceinline__ void dist_group4(const float* __restrict__ lat,
                                            const float* __restrict__ lon,
                                            const float* __restrict__ hh,
                                            const float* __restrict__ px,
                                            const float* __restrict__ py,
                                            const float* __restrict__ pz,
                                            float* __restrict__ dout) {
    const float D2R = (float)0.017453292519943295;   // fp32 deg2rad, matches numpy
    double x[8], s8[8], c8[8];
#pragma unroll
    for (int j = 0; j < 4; ++j) x[j] = (double)(lat[j] * D2R);
#pragma unroll
    for (int j = 0; j < 4; ++j) x[4 + j] = (double)(lon[j] * D2R);
    sincos8(x, s8, c8);

    const double A = 6378137.0, E2 = 0.00669437999014;
#pragma unroll
    for (int j = 0; j < 4; ++j) {
        double sl = s8[j], cl = c8[j], so = s8[4 + j], co = c8[4 + j];
        double h = (double)hh[j];
        double w = fma(-E2 * sl, sl, 1.0);            // [0.9933, 1]
        double y0 = (double)__frsqrt_rn((float)w);    // ~1e-7 rel seed
        double y = y0 * fma(-0.5 * w, y0 * y0, 1.5);  // 1 Newton -> ~1.5e-14
        double N = A * y, Nh = N + h;
        double clh = Nh * cl;
        double X = clh * co;
        double Y = clh * so;
        double Z = fma(N, -E2, N + h) * sl;           // (N*(1-E2)+h)*sl
        double dx = (double)px[j] - X;
        double dy = (double)py[j] - Y;
        double dz = (double)pz[j] - Z;
        dout[j] = sqrtf((float)(dx * dx + dy * dy + dz * dz));
    }
}

// scalar path for the tail
__device__ __forceinline__ float dist_one(float latd, float lond, float hf,
                                          float pxx, float pyy, float pzz) {
    float lat[4] = {latd, latd, latd, latd}, lon[4] = {lond, lond, lond, lond};
    float hh[4] = {hf, hf, hf, hf};
    float px[4] = {pxx, pxx, pxx, pxx}, py[4] = {pyy, pyy, pyy, pyy}, pz[4] = {pzz, pzz, pzz, pzz};
    float d[4];
    dist_group4(lat, lon, hh, px, py, pz, d);
    return d[0];
}

#define UNPACK4(ta, tb, tc, lat, lon, hh)                         \
    float lat[4] = {ta.x, ta.w, tb.z, tc.y};                      \
    float lon[4] = {ta.y, tb.x, tb.w, tc.z};                      \
    float hh[4]  = {ta.z, tb.y, tc.x, tc.w};

// pack 4 fp32 -> 4 fp16 as one 8-byte store
__device__ __forceinline__ void store_half4(__half* p, float d0, float d1, float d2, float d3) {
    union { __half2 h2[2]; uint2 u; } pk;
    pk.h2[0] = __floats2half2_rn(d0, d1);
    pk.h2[1] = __floats2half2_rn(d2, d3);
    *(uint2*)p = pk.u;
}

__global__ __launch_bounds__(THREADS, 4)
void k_pass1(const float* __restrict__ inp, const float* __restrict__ tgt,
             __half* __restrict__ dist_arr, float* __restrict__ blockmax, long B) {
    long ngroups = (B + 3) >> 2;
    long gstride = (long)gridDim.x * blockDim.x;
    float lmax = 0.0f;
    for (long g = (long)blockIdx.x * blockDim.x + threadIdx.x; g < ngroups; g += gstride) {
        long base = g << 2;
        if (base + 3 < B) {
            const float4* t4 = (const float4*)(tgt + 3 * base);
            const float4* p4 = (const float4*)(inp + 3 * base);
            float4 ta = t4[0], tb = t4[1], tc = t4[2];
            float4 pa = p4[0], pb = p4[1], pc = p4[2];

            UNPACK4(ta, tb, tc, lat, lon, hh);
            UNPACK4(pa, pb, pc, px, py, pz);
            float d[4];
            dist_group4(lat, lon, hh, px, py, pz, d);

            if (dist_arr)
                store_half4(dist_arr + base, d[0], d[1], d[2], d[3]);
            lmax = fmaxf(lmax, fmaxf(fmaxf(d[0], d[1]), fmaxf(d[2], d[3])));
        } else {
            long end = base + 4 < B ? base + 4 : B;
            for (long i = base; i < end; ++i) {
                float d = dist_one(tgt[3*i], tgt[3*i+1], tgt[3*i+2],
                                   inp[3*i], inp[3*i+1], inp[3*i+2]);
                if (dist_arr) dist_arr[i] = __float2half_rn(d);
                lmax = fmaxf(lmax, d);
            }
        }
    }
    for (int off = 32; off > 0; off >>= 1)
        lmax = fmaxf(lmax, __shfl_down(lmax, off, 64));
    __shared__ float smax[THREADS / 64];
    if ((threadIdx.x & 63) == 0) smax[threadIdx.x >> 6] = lmax;
    __syncthreads();
    if (threadIdx.x == 0) {
        float m = smax[0];
        for (int w = 1; w < THREADS / 64; ++w) m = fmaxf(m, smax[w]);
        blockmax[blockIdx.x] = m;
    }
}

__device__ __forceinline__ double focal2(float d, float invden) {
    float g = 2.0f * __expf(-d);                  // dynamic gamma (SCALE=1, GAMMA=2)
    float b = 1.0f - sqrtf(d * invden);           // hoisted reciprocal
    b = fmaxf(b, 0.0f);                           // guards fp16 round-up past max
    float wgt = __builtin_amdgcn_exp2f(g * __log2f(b));  // b^g; log2(0)->-inf->0 ok
    float fl = wgt * d;                           // ALPHA = 1
    return (double)fl * (double)fl;
}

__global__ void k_pass2(const __half* __restrict__ dist_arr,
                        const float* __restrict__ inp,
                        const float* __restrict__ tgt,
                        const float* __restrict__ blockmax, int nb1,
                        double* __restrict__ partials, long B) {
    __shared__ float smax[THREADS / 64];
    __shared__ double sacc[THREADS / 64];
    __shared__ float sb;
    int tid = threadIdx.x;

    // fold blockmax inline (nb1 floats, L2-hot)
    float m = 0.0f;
    for (int i = tid; i < nb1; i += THREADS) m = fmaxf(m, blockmax[i]);
    for (int off = 32; off > 0; off >>= 1)
        m = fmaxf(m, __shfl_down(m, off, 64));
    if ((tid & 63) == 0) smax[tid >> 6] = m;
    __syncthreads();
    if (tid == 0) {
        float mm = smax[0];
        for (int w = 1; w < THREADS / 64; ++w) mm = fmaxf(mm, smax[w]);
        sb = mm;
    }
    __syncthreads();
    float invden = 1.0f / (sb + 1e-8f);           // one true div per thread

    long ngroups = (B + 3) >> 2;
    long gstride = (long)gridDim.x * blockDim.x;
    double acc = 0.0;
    for (long g = (long)blockIdx.x * blockDim.x + tid; g < ngroups; g += gstride) {
        long base = g << 2;
        if (base + 3 < B) {
            float d0, d1, d2, d3;
            if (dist_arr) {
                union { uint2 u; __half2 h2[2]; } pk;
                pk.u = *(const uint2*)(dist_arr + base);
                float2 lo = __half22float2(pk.h2[0]);
                float2 hi = __half22float2(pk.h2[1]);
                d0 = lo.x; d1 = lo.y; d2 = hi.x; d3 = hi.y;
            } else {
                const float4* t4 = (const float4*)(tgt + 3 * base);
                float4 ta = t4[0], tb = t4[1], tc = t4[2];
                const float4* p4 = (const float4*)(inp + 3 * base);
                float4 pa = p4[0], pb = p4[1], pc = p4[2];
                UNPACK4(ta, tb, tc, lat, lon, hh);
                UNPACK4(pa, pb, pc, px, py, pz);
                float d[4];
                dist_group4(lat, lon, hh, px, py, pz, d);
                d0 = d[0]; d1 = d[1]; d2 = d[2]; d3 = d[3];
            }
            acc += focal2(d0, invden) + focal2(d1, invden)
                 + focal2(d2, invden) + focal2(d3, invden);
        } else {
            for (long i = base; i < B; ++i) {
                float d = dist_arr ? __half2float(dist_arr[i])
                                   : dist_one(tgt[3*i], tgt[3*i+1], tgt[3*i+2],
                                              inp[3*i], inp[3*i+1], inp[3*i+2]);
                acc += focal2(d, invden);
            }
        }
    }
    for (int off = 32; off > 0; off >>= 1)
        acc += __shfl_down(acc, off, 64);
    if ((tid & 63) == 0) sacc[tid >> 6] = acc;
    __syncthreads();
    if (tid == 0) {
        double s = sacc[0];
        for (int w = 1; w < THREADS / 64; ++w) s += sacc[w];
        partials[blockIdx.x] = s;
    }
}

__global__ void k_final(const double* __restrict__ partials, int nparts,
                        float* __restrict__ out, long B) {
    double acc = 0.0;
    for (int i = threadIdx.x; i < nparts; i += blockDim.x) acc += partials[i];
    for (int off = 32; off > 0; off >>= 1)
        acc += __shfl_down(acc, off, 64);
    __shared__ double lds[THREADS / 64];
    if ((threadIdx.x & 63) == 0) lds[threadIdx.x >> 6] = acc;
    __syncthreads();
    if (threadIdx.x == 0) {
        double s = lds[0];
        for (int w = 1; w < THREADS / 64; ++w) s += lds[w];
        out[0] = (float)sqrt(s / (double)B);
    }
}

extern "C" void kernel_launch(void* const* d_in, const int* in_sizes, int n_in,
                              void* d_out, int out_size, void* d_ws, size_t ws_size,
                              hipStream_t stream) {
    const float* inp = (const float*)d_in[0];   // (B,3) predicted ECEF
    const float* tgt = (const float*)d_in[1];   // (B,3) geodetic lat/lon/h
    float* out = (float*)d_out;
    long B = (long)in_sizes[0] / 3;

    float* blockmax = (float*)((char*)d_ws + BMAX_OFF);
    double* partials = (double*)((char*)d_ws + PART_OFF);
    __half* dist_arr = nullptr;
    size_t need = (size_t)DIST_OFF + (size_t)B * sizeof(__half);
    if (ws_size >= need) dist_arr = (__half*)((char*)d_ws + DIST_OFF);

    long ngroups = (B + 3) >> 2;

    // pass1: 1 group per thread, 4 waves/SIMD target
    int nb1 = (int)((ngroups + THREADS - 1) / THREADS);
    if (nb1 > PART_CAP) nb1 = PART_CAP;
    if (nb1 < 1) nb1 = 1;

    // pass2: grid-stride, capped (halves blockmax broadcast + final fold)
    int nb2 = (int)((ngroups + THREADS - 1) / THREADS);
    if (nb2 > NB2_CAP) nb2 = NB2_CAP;
    if (nb2 < 1) nb2 = 1;

    k_pass1<<<nb1, THREADS, 0, stream>>>(inp, tgt, dist_arr, blockmax, B);
    k_pass2<<<nb2, THREADS, 0, stream>>>(dist_arr, inp, tgt, blockmax, nb1, partials, B);
    k_final<<<1, THREADS, 0, stream>>>(partials, nb2, out, B);
}

// Round 5
// 127.237 us; speedup vs baseline: 1.0070x; 1.0070x over previous
//
#include <hip/hip_runtime.h>
#include <hip/hip_fp16.h>
#include <math.h>

// ---------------------------------------------------------------------------
// FocalLoss: geodetic->ECEF->ENU error -> distance -> focal-weighted RMS.
// 3-kernel pipeline: pass1 (dist -> fp16 ws, per-block max) ->
// pass2 (fold blockmax inline + focal + per-block partial) -> final.
//
// R17 = R16 with pass1 register diet (breadth-4 sincos x2 instead of
// breadth-8).
// R16 post-mortem: neutral vs R15. lb(256,4) demands <=128 VGPR but the
// breadth-8 sincos needs ~96 VGPR live by data flow alone -> compiler must
// spill to scratch; spill cost canceled the 4th-wave occupancy gain.
// R17: two sequential breadth-4 sincos calls (lat quartet, then lon
// quartet). Peak live ~100 VGPR -> no spills at lb(256,4), 16 waves/CU.
// Per-element math operation-identical to R16 (numerics unchanged).
// Kept: fp32 range reduction (exact identity for any integer k), fp32 poly
// tails, fp32 rsqrt seed + 1 dp Newton, pass2 1/denom hoist, NB2_CAP=2048,
// no nt loads (R14 lesson).
// ---------------------------------------------------------------------------

#define THREADS 256
#define PART_CAP 8192
#define NB2_CAP 2048
#define BMAX_OFF 64
#define PART_OFF (64 + PART_CAP * 4)                 // doubles, 8-aligned
#define DIST_OFF (1 << 20)                           // 1 MB, 16B-aligned

// ---- 4-wide breadth-first sincos, |x| <= ~3.15 (no Payne-Hanek) ----------
// fdlibm minimax; 4 leading Horner stages in fp32 (contribution < 1e-4,
// fp32 rounding there adds < 2e-10 abs), final stage + combine in fp64.
// Quadrant via fp32 rintf: identity sin(x)=f(r,q) exact for any integer k.
// Total abs err ~1e-10 -> ~1e-3 m at N=6.4e6.
__device__ __forceinline__ void sincos4(const double* __restrict__ x,
                                        double* __restrict__ s,
                                        double* __restrict__ c) {
    const float  TWO_OVER_PI_F = 0.636619772367581343076f;
    const double PIO2_HI = 1.57079632679489655800e+00;
    const double PIO2_LO = 6.12323399573676603587e-17;

    double kd[4], r[4], r2[4];
    int q[4];
#pragma unroll
    for (int j = 0; j < 4; ++j) {
        float kf = rintf((float)x[j] * TWO_OVER_PI_F);
        kd[j] = (double)kf;
        q[j] = ((int)kf) & 3;
    }
#pragma unroll
    for (int j = 0; j < 4; ++j) {
        double rr = fma(-kd[j], PIO2_HI, x[j]);
        r[j] = fma(-kd[j], PIO2_LO, rr);
        r2[j] = r[j] * r[j];
    }
    // fp32 high-order tails
    float rf[4], psf[4], pcf[4];
#pragma unroll
    for (int j = 0; j < 4; ++j) rf[j] = (float)r2[j];
#pragma unroll
    for (int j = 0; j < 4; ++j) { psf[j] = -2.50507602534068634195e-08f;
                                  pcf[j] =  2.08757232129817482790e-09f; }
#pragma unroll
    for (int j = 0; j < 4; ++j) { psf[j] = fmaf(psf[j], rf[j],  2.75573137070700676789e-06f);
                                  pcf[j] = fmaf(pcf[j], rf[j], -2.75573143513906633035e-07f); }
#pragma unroll
    for (int j = 0; j < 4; ++j) { psf[j] = fmaf(psf[j], rf[j], -1.98412698298579493134e-04f);
                                  pcf[j] = fmaf(pcf[j], rf[j],  2.48015872894767294178e-05f); }
#pragma unroll
    for (int j = 0; j < 4; ++j) { psf[j] = fmaf(psf[j], rf[j],  8.33333333332248946124e-03f);
                                  pcf[j] = fmaf(pcf[j], rf[j], -1.38888888888741095749e-03f); }
#pragma unroll
    for (int j = 0; j < 4; ++j) {
        double ps = fma((double)psf[j], r2[j], -1.66666666666666324348e-01);
        double pc = fma((double)pcf[j], r2[j],  4.16666666666666019037e-02);
        double sv = fma(r2[j] * r[j], ps, r[j]);
        double cv = fma(r2[j] * r2[j], pc, fma(-0.5, r2[j], 1.0));
        double sr = (q[j] & 1) ? cv : sv;
        double cr = (q[j] & 1) ? sv : cv;
        s[j] = (q[j] & 2) ? -sr : sr;
        c[j] = ((q[j] + 1) & 2) ? -cr : cr;
    }
}

// ---- 4 elements; lat sincos then lon sincos (sequential = low VGPR peak);
// NO rotation (|R d| == |d|) ----
__device__ __forceinline__ void dist_group4(const float* __restrict__ lat,
                                            const float* __restrict__ lon,
                                            const float* __restrict__ hh,
                                            const float* __restrict__ px,
                                            const float* __restrict__ py,
                                            const float* __restrict__ pz,
                                            float* __restrict__ dout) {
    const float D2R = (float)0.017453292519943295;   // fp32 deg2rad, matches numpy
    double xl[4], sl[4], cl[4];
#pragma unroll
    for (int j = 0; j < 4; ++j) xl[j] = (double)(lat[j] * D2R);
    sincos4(xl, sl, cl);

    double xo[4], so[4], co[4];
#pragma unroll
    for (int j = 0; j < 4; ++j) xo[j] = (double)(lon[j] * D2R);
    sincos4(xo, so, co);

    const double A = 6378137.0, E2 = 0.00669437999014;
#pragma unroll
    for (int j = 0; j < 4; ++j) {
        double h = (double)hh[j];
        double w = fma(-E2 * sl[j], sl[j], 1.0);      // [0.9933, 1]
        double y0 = (double)__frsqrt_rn((float)w);    // ~1e-7 rel seed
        double y = y0 * fma(-0.5 * w, y0 * y0, 1.5);  // 1 Newton -> ~1.5e-14
        double N = A * y, Nh = N + h;
        double clh = Nh * cl[j];
        double X = clh * co[j];
        double Y = clh * so[j];
        double Z = fma(N, -E2, N + h) * sl[j];        // (N*(1-E2)+h)*sl
        double dx = (double)px[j] - X;
        double dy = (double)py[j] - Y;
        double dz = (double)pz[j] - Z;
        dout[j] = sqrtf((float)(dx * dx + dy * dy + dz * dz));
    }
}

// scalar path for the tail
__device__ __forceinline__ float dist_one(float latd, float lond, float hf,
                                          float pxx, float pyy, float pzz) {
    float lat[4] = {latd, latd, latd, latd}, lon[4] = {lond, lond, lond, lond};
    float hh[4] = {hf, hf, hf, hf};
    float px[4] = {pxx, pxx, pxx, pxx}, py[4] = {pyy, pyy, pyy, pyy}, pz[4] = {pzz, pzz, pzz, pzz};
    float d[4];
    dist_group4(lat, lon, hh, px, py, pz, d);
    return d[0];
}

#define UNPACK4(ta, tb, tc, lat, lon, hh)                         \
    float lat[4] = {ta.x, ta.w, tb.z, tc.y};                      \
    float lon[4] = {ta.y, tb.x, tb.w, tc.z};                      \
    float hh[4]  = {ta.z, tb.y, tc.x, tc.w};

// pack 4 fp32 -> 4 fp16 as one 8-byte store
__device__ __forceinline__ void store_half4(__half* p, float d0, float d1, float d2, float d3) {
    union { __half2 h2[2]; uint2 u; } pk;
    pk.h2[0] = __floats2half2_rn(d0, d1);
    pk.h2[1] = __floats2half2_rn(d2, d3);
    *(uint2*)p = pk.u;
}

__global__ __launch_bounds__(THREADS, 4)
void k_pass1(const float* __restrict__ inp, const float* __restrict__ tgt,
             __half* __restrict__ dist_arr, float* __restrict__ blockmax, long B) {
    long ngroups = (B + 3) >> 2;
    long gstride = (long)gridDim.x * blockDim.x;
    float lmax = 0.0f;
    for (long g = (long)blockIdx.x * blockDim.x + threadIdx.x; g < ngroups; g += gstride) {
        long base = g << 2;
        if (base + 3 < B) {
            const float4* t4 = (const float4*)(tgt + 3 * base);
            const float4* p4 = (const float4*)(inp + 3 * base);
            float4 ta = t4[0], tb = t4[1], tc = t4[2];
            float4 pa = p4[0], pb = p4[1], pc = p4[2];

            UNPACK4(ta, tb, tc, lat, lon, hh);
            UNPACK4(pa, pb, pc, px, py, pz);
            float d[4];
            dist_group4(lat, lon, hh, px, py, pz, d);

            if (dist_arr)
                store_half4(dist_arr + base, d[0], d[1], d[2], d[3]);
            lmax = fmaxf(lmax, fmaxf(fmaxf(d[0], d[1]), fmaxf(d[2], d[3])));
        } else {
            long end = base + 4 < B ? base + 4 : B;
            for (long i = base; i < end; ++i) {
                float d = dist_one(tgt[3*i], tgt[3*i+1], tgt[3*i+2],
                                   inp[3*i], inp[3*i+1], inp[3*i+2]);
                if (dist_arr) dist_arr[i] = __float2half_rn(d);
                lmax = fmaxf(lmax, d);
            }
        }
    }
    for (int off = 32; off > 0; off >>= 1)
        lmax = fmaxf(lmax, __shfl_down(lmax, off, 64));
    __shared__ float smax[THREADS / 64];
    if ((threadIdx.x & 63) == 0) smax[threadIdx.x >> 6] = lmax;
    __syncthreads();
    if (threadIdx.x == 0) {
        float m = smax[0];
        for (int w = 1; w < THREADS / 64; ++w) m = fmaxf(m, smax[w]);
        blockmax[blockIdx.x] = m;
    }
}

__device__ __forceinline__ double focal2(float d, float invden) {
    float g = 2.0f * __expf(-d);                  // dynamic gamma (SCALE=1, GAMMA=2)
    float b = 1.0f - sqrtf(d * invden);           // hoisted reciprocal
    b = fmaxf(b, 0.0f);                           // guards fp16 round-up past max
    float wgt = __builtin_amdgcn_exp2f(g * __log2f(b));  // b^g; log2(0)->-inf->0 ok
    float fl = wgt * d;                           // ALPHA = 1
    return (double)fl * (double)fl;
}

__global__ void k_pass2(const __half* __restrict__ dist_arr,
                        const float* __restrict__ inp,
                        const float* __restrict__ tgt,
                        const float* __restrict__ blockmax, int nb1,
                        double* __restrict__ partials, long B) {
    __shared__ float smax[THREADS / 64];
    __shared__ double sacc[THREADS / 64];
    __shared__ float sb;
    int tid = threadIdx.x;

    // fold blockmax inline (nb1 floats, L2-hot)
    float m = 0.0f;
    for (int i = tid; i < nb1; i += THREADS) m = fmaxf(m, blockmax[i]);
    for (int off = 32; off > 0; off >>= 1)
        m = fmaxf(m, __shfl_down(m, off, 64));
    if ((tid & 63) == 0) smax[tid >> 6] = m;
    __syncthreads();
    if (tid == 0) {
        float mm = smax[0];
        for (int w = 1; w < THREADS / 64; ++w) mm = fmaxf(mm, smax[w]);
        sb = mm;
    }
    __syncthreads();
    float invden = 1.0f / (sb + 1e-8f);           // one true div per thread

    long ngroups = (B + 3) >> 2;
    long gstride = (long)gridDim.x * blockDim.x;
    double acc = 0.0;
    for (long g = (long)blockIdx.x * blockDim.x + tid; g < ngroups; g += gstride) {
        long base = g << 2;
        if (base + 3 < B) {
            float d0, d1, d2, d3;
            if (dist_arr) {
                union { uint2 u; __half2 h2[2]; } pk;
                pk.u = *(const uint2*)(dist_arr + base);
                float2 lo = __half22float2(pk.h2[0]);
                float2 hi = __half22float2(pk.h2[1]);
                d0 = lo.x; d1 = lo.y; d2 = hi.x; d3 = hi.y;
            } else {
                const float4* t4 = (const float4*)(tgt + 3 * base);
                float4 ta = t4[0], tb = t4[1], tc = t4[2];
                const float4* p4 = (const float4*)(inp + 3 * base);
                float4 pa = p4[0], pb = p4[1], pc = p4[2];
                UNPACK4(ta, tb, tc, lat, lon, hh);
                UNPACK4(pa, pb, pc, px, py, pz);
                float d[4];
                dist_group4(lat, lon, hh, px, py, pz, d);
                d0 = d[0]; d1 = d[1]; d2 = d[2]; d3 = d[3];
            }
            acc += focal2(d0, invden) + focal2(d1, invden)
                 + focal2(d2, invden) + focal2(d3, invden);
        } else {
            for (long i = base; i < B; ++i) {
                float d = dist_arr ? __half2float(dist_arr[i])
                                   : dist_one(tgt[3*i], tgt[3*i+1], tgt[3*i+2],
                                              inp[3*i], inp[3*i+1], inp[3*i+2]);
                acc += focal2(d, invden);
            }
        }
    }
    for (int off = 32; off > 0; off >>= 1)
        acc += __shfl_down(acc, off, 64);
    if ((tid & 63) == 0) sacc[tid >> 6] = acc;
    __syncthreads();
    if (tid == 0) {
        double s = sacc[0];
        for (int w = 1; w < THREADS / 64; ++w) s += sacc[w];
        partials[blockIdx.x] = s;
    }
}

__global__ void k_final(const double* __restrict__ partials, int nparts,
                        float* __restrict__ out, long B) {
    double acc = 0.0;
    for (int i = threadIdx.x; i < nparts; i += blockDim.x) acc += partials[i];
    for (int off = 32; off > 0; off >>= 1)
        acc += __shfl_down(acc, off, 64);
    __shared__ double lds[THREADS / 64];
    if ((threadIdx.x & 63) == 0) lds[threadIdx.x >> 6] = acc;
    __syncthreads();
    if (threadIdx.x == 0) {
        double s = lds[0];
        for (int w = 1; w < THREADS / 64; ++w) s += lds[w];
        out[0] = (float)sqrt(s / (double)B);
    }
}

extern "C" void kernel_launch(void* const* d_in, const int* in_sizes, int n_in,
                              void* d_out, int out_size, void* d_ws, size_t ws_size,
                              hipStream_t stream) {
    const float* inp = (const float*)d_in[0];   // (B,3) predicted ECEF
    const float* tgt = (const float*)d_in[1];   // (B,3) geodetic lat/lon/h
    float* out = (float*)d_out;
    long B = (long)in_sizes[0] / 3;

    float* blockmax = (float*)((char*)d_ws + BMAX_OFF);
    double* partials = (double*)((char*)d_ws + PART_OFF);
    __half* dist_arr = nullptr;
    size_t need = (size_t)DIST_OFF + (size_t)B * sizeof(__half);
    if (ws_size >= need) dist_arr = (__half*)((char*)d_ws + DIST_OFF);

    long ngroups = (B + 3) >> 2;

    // pass1: 1 group per thread, 4 waves/SIMD target (no spills w/ breadth-4)
    int nb1 = (int)((ngroups + THREADS - 1) / THREADS);
    if (nb1 > PART_CAP) nb1 = PART_CAP;
    if (nb1 < 1) nb1 = 1;

    // pass2: grid-stride, capped (halves blockmax broadcast + final fold)
    int nb2 = (int)((ngroups + THREADS - 1) / THREADS);
    if (nb2 > NB2_CAP) nb2 = NB2_CAP;
    if (nb2 < 1) nb2 = 1;

    k_pass1<<<nb1, THREADS, 0, stream>>>(inp, tgt, dist_arr, blockmax, B);
    k_pass2<<<nb2, THREADS, 0, stream>>>(dist_arr, inp, tgt, blockmax, nb1, partials, B);
    k_final<<<1, THREADS, 0, stream>>>(partials, nb2, out, B);
}